// Round 18
// baseline (481.538 us; speedup 1.0000x reference)
//
#include <hip/hip_runtime.h>
#include <hip/hip_bf16.h>

#define NTOK 32768
#define NE 64
#define HD 1024
#define CAP 1280
#define NKF (NTOK*2)      // 65536 flat (token,k)
#define NSLOT (NE*CAP)    // 81920
#define NTILE 128         // dispatch tiles of 512 items (256 tokens)

typedef __attribute__((ext_vector_type(8))) short bf16x8;
typedef __attribute__((ext_vector_type(4))) short bf16x4;
typedef __attribute__((ext_vector_type(4))) float f32x4;
typedef __attribute__((ext_vector_type(4))) unsigned short u16x4;

// zero A-row page: .bss (zeroed at module load, never written)
__device__ __hip_bfloat16 g_zero[1152];

__device__ __forceinline__ short f2bf(float f) {
  union { __hip_bfloat16 b; short s; } u;
  u.b = __float2bfloat16(f);
  return u.s;
}
__device__ __forceinline__ float bf2f(unsigned short h) {
  return __uint_as_float(((unsigned)h) << 16);
}

// ---- gating: logits[N,64] = x @ gw^T (fp32) + emit bf16 xb, convw INTERLEAVED ----
// 512 threads, 256 tokens/block, per-thread 8x4 tile (LDS:VALU 1.5:1 vs old 2:1).
// Each logit's FMA chain stays strictly k-sequential (chunk-major, kk, xyzw) ->
// bit-identical to the verified R6 arithmetic. convw: 8 grid-stride steps per chunk.
__global__ __launch_bounds__(512) void gating_kernel(const float* __restrict__ x,
                                                     const float* __restrict__ gw,
                                                     float* __restrict__ logits,
                                                     __hip_bfloat16* __restrict__ xb,
                                                     const float* __restrict__ ew,
                                                     __hip_bfloat16* __restrict__ wb) {
  __shared__ float Xs[256][66];
  __shared__ float Gs[64][66];
  const int tid = threadIdx.x;
  const int tok0 = blockIdx.x * 256;
  const int th = tid >> 4;   // token sub-row 0..31; tokens th + i*32
  const int te = tid & 15;   // expert sub-col 0..15; experts te + j*16
  float acc[8][4];
#pragma unroll
  for (int i = 0; i < 8; ++i)
#pragma unroll
    for (int j = 0; j < 4; ++j) acc[i][j] = 0.f;

  // convw: 67.1M floats / (128 blk * 512 th * 8 per step) = 128 steps; 8 per chunk
  size_t ci = ((size_t)blockIdx.x * 512 + tid) * 8;
  const size_t cstride = (size_t)128 * 512 * 8;

  for (int k0i = 0; k0i < 16; ++k0i) {
    const int k0 = k0i * 64;
    // stage x tile (256 rows x 64 k) + emit xb
#pragma unroll
    for (int r = 0; r < 8; ++r) {
      int idx = r * 512 + tid;
      int row = idx >> 4;
      int c = (idx & 15) * 4;
      float4 xv4 = *(const float4*)&x[(size_t)(tok0 + row) * HD + k0 + c];
      *(float4*)&Xs[row][c] = xv4;
      bf16x4 o;
      o[0] = f2bf(xv4.x); o[1] = f2bf(xv4.y); o[2] = f2bf(xv4.z); o[3] = f2bf(xv4.w);
      *(bf16x4*)&xb[(size_t)(tok0 + row) * HD + k0 + c] = o;
    }
    // stage gw tile (64 rows x 64 k)
#pragma unroll
    for (int r = 0; r < 2; ++r) {
      int idx = r * 512 + tid;
      int row = idx >> 4;
      int c = (idx & 15) * 4;
      *(float4*)&Gs[row][c] = *(const float4*)&gw[(size_t)row * HD + k0 + c];
    }
    // issue convw batch 0
    float4 ca[4], cb[4];
#pragma unroll
    for (int q = 0; q < 4; ++q) {
      ca[q] = *(const float4*)(ew + ci + (size_t)q * cstride);
      cb[q] = *(const float4*)(ew + ci + (size_t)q * cstride + 4);
    }
    __syncthreads();
#pragma unroll 4
    for (int kk = 0; kk < 8; ++kk) {
      float4 xv[8], gv[4];
#pragma unroll
      for (int i = 0; i < 8; ++i) xv[i] = *(float4*)&Xs[th + i * 32][kk * 4];
#pragma unroll
      for (int j = 0; j < 4; ++j) gv[j] = *(float4*)&Gs[te + j * 16][kk * 4];
#pragma unroll
      for (int i = 0; i < 8; ++i)
#pragma unroll
        for (int j = 0; j < 4; ++j) {
          acc[i][j] = fmaf(xv[i].x, gv[j].x, acc[i][j]);
          acc[i][j] = fmaf(xv[i].y, gv[j].y, acc[i][j]);
          acc[i][j] = fmaf(xv[i].z, gv[j].z, acc[i][j]);
          acc[i][j] = fmaf(xv[i].w, gv[j].w, acc[i][j]);
        }
    }
    // store batch 0, issue batch 1
#pragma unroll
    for (int q = 0; q < 4; ++q) {
      bf16x8 o;
      o[0] = f2bf(ca[q].x); o[1] = f2bf(ca[q].y); o[2] = f2bf(ca[q].z); o[3] = f2bf(ca[q].w);
      o[4] = f2bf(cb[q].x); o[5] = f2bf(cb[q].y); o[6] = f2bf(cb[q].z); o[7] = f2bf(cb[q].w);
      *(bf16x8*)(wb + ci + (size_t)q * cstride) = o;
    }
#pragma unroll
    for (int q = 0; q < 4; ++q) {
      ca[q] = *(const float4*)(ew + ci + (size_t)(q + 4) * cstride);
      cb[q] = *(const float4*)(ew + ci + (size_t)(q + 4) * cstride + 4);
    }
#pragma unroll 4
    for (int kk = 8; kk < 16; ++kk) {
      float4 xv[8], gv[4];
#pragma unroll
      for (int i = 0; i < 8; ++i) xv[i] = *(float4*)&Xs[th + i * 32][kk * 4];
#pragma unroll
      for (int j = 0; j < 4; ++j) gv[j] = *(float4*)&Gs[te + j * 16][kk * 4];
#pragma unroll
      for (int i = 0; i < 8; ++i)
#pragma unroll
        for (int j = 0; j < 4; ++j) {
          acc[i][j] = fmaf(xv[i].x, gv[j].x, acc[i][j]);
          acc[i][j] = fmaf(xv[i].y, gv[j].y, acc[i][j]);
          acc[i][j] = fmaf(xv[i].z, gv[j].z, acc[i][j]);
          acc[i][j] = fmaf(xv[i].w, gv[j].w, acc[i][j]);
        }
    }
#pragma unroll
    for (int q = 0; q < 4; ++q) {
      bf16x8 o;
      o[0] = f2bf(ca[q].x); o[1] = f2bf(ca[q].y); o[2] = f2bf(ca[q].z); o[3] = f2bf(ca[q].w);
      o[4] = f2bf(cb[q].x); o[5] = f2bf(cb[q].y); o[6] = f2bf(cb[q].z); o[7] = f2bf(cb[q].w);
      *(bf16x8*)(wb + ci + (size_t)(q + 4) * cstride) = o;
    }
    ci += (size_t)8 * cstride;
    __syncthreads();
  }
#pragma unroll
  for (int i = 0; i < 8; ++i)
#pragma unroll
    for (int j = 0; j < 4; ++j)
      logits[(size_t)(tok0 + th + i * 32) * NE + te + j * 16] = acc[i][j];
}

// ------- fused top-2 + probs + importance + per-tile stable rank + histogram -------
__global__ __launch_bounds__(256) void topk_hist_kernel(const float* __restrict__ logits,
                                                        int2* __restrict__ e01,
                                                        float2* __restrict__ p01,
                                                        float* __restrict__ imp_part,
                                                        int* __restrict__ rank_buf,
                                                        int* __restrict__ hist) {
  __shared__ int wh[4][64];
  const int tid = threadIdx.x;
  const int w = tid >> 6, lane = tid & 63;
  const int t = blockIdx.x * 256 + tid;
  float l[64];
  const float4* lp = (const float4*)(logits + (size_t)t * NE);
#pragma unroll
  for (int i = 0; i < 16; ++i) {
    float4 v = lp[i];
    l[4 * i] = v.x; l[4 * i + 1] = v.y; l[4 * i + 2] = v.z; l[4 * i + 3] = v.w;
  }
  float v1 = -1e30f; int i1 = 0;
#pragma unroll
  for (int j = 0; j < 64; ++j) if (l[j] > v1) { v1 = l[j]; i1 = j; }
  float v2 = -1e30f; int i2 = 0;
#pragma unroll
  for (int j = 0; j < 64; ++j) if (j != i1 && l[j] > v2) { v2 = l[j]; i2 = j; }
  float ex = __expf(v2 - v1);
  float inv2 = 1.f / (1.f + ex);
  e01[t] = make_int2(i1, i2);
  p01[t] = make_float2(inv2, ex * inv2);

  float s = 0.f;
#pragma unroll
  for (int j = 0; j < 64; ++j) s += __expf(l[j] - v1);
  float invs = 1.f / s;
  const int wid = t >> 6;
#pragma unroll
  for (int e = 0; e < 64; ++e) {
    float p = __expf(l[e] - v1) * invs;
#pragma unroll
    for (int off = 32; off; off >>= 1) p += __shfl_xor(p, off);
    if (lane == 0) imp_part[(size_t)wid * 64 + e] = p;
  }

  int r0 = 0, r1 = 0, cnt = 0;
#pragma unroll
  for (int j = 0; j < 64; ++j) {
    int a = __shfl(i1, j);
    int b = __shfl(i2, j);
    int ja = (j < lane);
    r0 += ja & (a == i1);
    r0 += ja & (b == i1);
    r1 += ja & (a == i2);
    r1 += ja & (b == i2);
    cnt += (a == lane) + (b == lane);
  }
  wh[w][lane] = cnt;
  __syncthreads();
#pragma unroll
  for (int ww = 0; ww < 4; ++ww)
    if (ww < w) { r0 += wh[ww][i1]; r1 += wh[ww][i2]; }
  rank_buf[2 * t] = r0;
  rank_buf[2 * t + 1] = r1;
  if (tid < 64)
    hist[blockIdx.x * 64 + tid] = wh[0][tid] + wh[1][tid] + wh[2][tid] + wh[3][tid];
}

// ------- place + distributed scan + aux -------
__global__ __launch_bounds__(512) void place_kernel(const int2* __restrict__ e01,
                                                    const int* __restrict__ rank_buf,
                                                    const int* __restrict__ hist,
                                                    const float* __restrict__ imp_part,
                                                    int* __restrict__ slot_of,
                                                    int* __restrict__ slot_token,
                                                    int* __restrict__ counts,
                                                    float* __restrict__ out) {
  __shared__ int toff[64];
  const int b = blockIdx.x;
  const int tid = threadIdx.x;
  if (tid < 64) {
    int run = 0;
    for (int t = 0; t < b; ++t) run += hist[t * 64 + tid];
    toff[tid] = run;
  }
  __syncthreads();
  const int i = b * 512 + tid;
  int2 ee = e01[i >> 1];
  const int e = (i & 1) ? ee.y : ee.x;
  const int pos = toff[e] + rank_buf[i];
  const int slot = (pos < CAP) ? (e * CAP + pos) : -1;
  slot_of[i] = slot;
  if (slot >= 0) slot_token[slot] = i;

  if (b == NTILE - 1 && tid < 64) {
    const int total = toff[tid] + hist[b * 64 + tid];
    counts[tid] = total;
    float imp = 0.f;
    for (int w = 0; w < 512; ++w) imp += imp_part[(size_t)w * 64 + tid];
    imp *= (1.f / (float)NTOK);
    float v = ((float)total / (float)NKF) * imp;
#pragma unroll
    for (int off = 32; off; off >>= 1) v += __shfl_xor(v, off);
    if (tid == 0) out[(size_t)NTOK * HD] = fminf(v * (float)NE * 0.01f, 1.0f);
  }
}

// -------- grouped expert GEMM: 256x256, BK=64, 8-wave, fused A-gather, 3-buf B ring --------
#define ASYNC16(g, l) __builtin_amdgcn_global_load_lds( \
    (const __attribute__((address_space(1))) void*)(g), \
    (__attribute__((address_space(3))) void*)(l), 16, 0, 0)

#define STAGE_A(buf, ks, kcol) do {                                             \
    const int _d = ((buf) * 16384 + (ks) * 8192 + wuni) * 2;                    \
    ASYNC16(arow0 + (kcol) + (ks) * 32 + sw8, (char*)lds + _d);                 \
    ASYNC16(arow1 + (kcol) + (ks) * 32 + sw8, (char*)lds + _d + 8192);          \
  } while (0)

#define STAGE_B3(buf3, ks, kcol) do {                                           \
    const __hip_bfloat16* _g = B + (size_t)srow * HD + (kcol) + (ks) * 32 + sw8; \
    const int _d = (32768 + (buf3) * 16384 + (ks) * 8192 + wuni) * 2;           \
    ASYNC16(_g, (char*)lds + _d);                                               \
    ASYNC16(_g + (size_t)128 * HD, (char*)lds + _d + 8192);                     \
  } while (0)

#define LDA(dst, buf, ks, mi) \
  dst = *(const bf16x8*)(lds + (buf) * 16384 + (ks) * 8192 + (wm * 128 + (mi) * 16 + fr) * 32 + rsw)
#define LDB3(dst, buf3, ks, ni) \
  dst = *(const bf16x8*)(lds + 32768 + (buf3) * 16384 + (ks) * 8192 + (wn * 64 + (ni) * 16 + fr) * 32 + rsw)

#define MFMA_HALF(h)                                                            \
  _Pragma("unroll")                                                             \
  for (int mm = 0; mm < 4; ++mm)                                                \
    _Pragma("unroll")                                                           \
    for (int nn = 0; nn < 4; ++nn)                                              \
      acc[(h) * 4 + mm][nn] =                                                   \
          __builtin_amdgcn_mfma_f32_16x16x32_bf16(av[mm], bv[nn], acc[(h) * 4 + mm][nn], 0, 0, 0)

#define BARX() do { asm volatile("" ::: "memory"); __builtin_amdgcn_s_barrier(); asm volatile("" ::: "memory"); } while (0)
#define VMC(n) asm volatile("s_waitcnt vmcnt(" #n ")" ::: "memory")

__global__ __launch_bounds__(512, 2) void moe_gemm_kernel(const __hip_bfloat16* __restrict__ xb,
                                                          const int* __restrict__ slot_token,
                                                          const __hip_bfloat16* __restrict__ Wb,
                                                          const int* __restrict__ counts,
                                                          __hip_bfloat16* __restrict__ Eo) {
  __shared__ __hip_bfloat16 lds[81920];  // 160 KB exactly

  const int bid = blockIdx.x;
  const int swz = (bid & 7) * 160 + (bid >> 3);
  const int e = swz / 20;
  const int t20 = swz - e * 20;
  const int tm = t20 >> 2, tn = t20 & 3;

  const int cnt = counts[e];
  if (tm * 256 >= cnt) return;  // capacity-tile skip

  const int tid = threadIdx.x;
  const int lane = tid & 63;
  const int w = tid >> 6;
  const int wm = w >> 2, wn = w & 3;

  const __hip_bfloat16* B = Wb + (size_t)e * HD * HD + (size_t)(tn * 256) * HD;

  const int srow = tid >> 2;
  const int sw8 = ((tid & 3) ^ ((tid >> 3) & 3)) * 8;
  const int wuni = w * 512;

  const int slotbase = e * CAP + tm * 256;
  const int r0row = tm * 256 + srow;
  const int i0 = slot_token[slotbase + srow];
  const int i1 = slot_token[slotbase + 128 + srow];
  const __hip_bfloat16* arow0 = (r0row < cnt) ? xb + (size_t)(i0 >> 1) * HD : g_zero;
  const __hip_bfloat16* arow1 = (r0row + 128 < cnt) ? xb + (size_t)(i1 >> 1) * HD : g_zero;

  const int fr = lane & 15;
  const int fq = lane >> 4;
  const int rsw = (fq ^ ((fr >> 1) & 3)) * 8;

  f32x4 acc[8][4] = {};

  STAGE_A(0, 0, 0);
  STAGE_A(0, 1, 0);
  STAGE_B3(0, 0, 0);
  STAGE_B3(0, 1, 0);
  STAGE_B3(1, 0, 64);
  STAGE_B3(1, 1, 64);
  VMC(4);
  BARX();

#pragma unroll 2
  for (int t = 0; t < 16; ++t) {
    const int ard = t & 1, ast = ard ^ 1;
    const int b_rd = t % 3;
    int b_st = b_rd + 2; if (b_st >= 3) b_st -= 3;
    const int kcA = (t + 1) * 64;
    const int kcB = (t + 2) * 64;
    const bool hA = (t < 15);
    const bool hB = (t < 14);
    bf16x8 av[4], bv[4];

    LDB3(bv[0], b_rd, 0, 0); LDB3(bv[1], b_rd, 0, 1); LDB3(bv[2], b_rd, 0, 2); LDB3(bv[3], b_rd, 0, 3);
    LDA(av[0], ard, 0, 0); LDA(av[1], ard, 0, 1); LDA(av[2], ard, 0, 2); LDA(av[3], ard, 0, 3);
    if (hA) STAGE_A(ast, 0, kcA);
    BARX();
    __builtin_amdgcn_s_setprio(1);
    MFMA_HALF(0);
    __builtin_amdgcn_s_setprio(0);
    BARX();

    LDA(av[0], ard, 0, 4); LDA(av[1], ard, 0, 5); LDA(av[2], ard, 0, 6); LDA(av[3], ard, 0, 7);
    if (hB) {
      STAGE_B3(b_st, 0, kcB);
      VMC(6);
    } else if (t == 14) {
      VMC(4);
    } else {
      VMC(0);
    }
    BARX();
    __builtin_amdgcn_s_setprio(1);
    MFMA_HALF(1);
    __builtin_amdgcn_s_setprio(0);
    BARX();

    LDB3(bv[0], b_rd, 1, 0); LDB3(bv[1], b_rd, 1, 1); LDB3(bv[2], b_rd, 1, 2); LDB3(bv[3], b_rd, 1, 3);
    LDA(av[0], ard, 1, 0); LDA(av[1], ard, 1, 1); LDA(av[2], ard, 1, 2); LDA(av[3], ard, 1, 3);
    if (hA) STAGE_A(ast, 1, kcA);
    BARX();
    __builtin_amdgcn_s_setprio(1);
    MFMA_HALF(0);
    __builtin_amdgcn_s_setprio(0);
    BARX();

    LDA(av[0], ard, 1, 4); LDA(av[1], ard, 1, 5); LDA(av[2], ard, 1, 6); LDA(av[3], ard, 1, 7);
    if (hB) {
      STAGE_B3(b_st, 1, kcB);
      VMC(6);
    } else if (t == 14) {
      VMC(2);
    }
    BARX();
    __builtin_amdgcn_s_setprio(1);
    MFMA_HALF(1);
    __builtin_amdgcn_s_setprio(0);
    BARX();
  }

  __hip_bfloat16* C = Eo + (size_t)e * CAP * HD +
                      (size_t)(tm * 256 + wm * 128) * HD + tn * 256 + wn * 64;
#pragma unroll
  for (int m = 0; m < 8; ++m)
#pragma unroll
    for (int n = 0; n < 4; ++n)
#pragma unroll
      for (int r = 0; r < 4; ++r)
        C[(size_t)(m * 16 + fq * 4 + r) * HD + n * 16 + fr] = __float2bfloat16(acc[m][n][r]);
}

// ---------------- combine (grid-stride, 2048 blocks) ----------------
__global__ __launch_bounds__(256) void combine_kernel(const __hip_bfloat16* __restrict__ eo,
                                                      const int* __restrict__ slot_of,
                                                      const float2* __restrict__ p01,
                                                      float* __restrict__ out) {
  const int tid = threadIdx.x;
  for (int t = blockIdx.x; t < NTOK; t += 2048) {
    const float2 p = p01[t];
    const int s0 = slot_of[2 * t], s1 = slot_of[2 * t + 1];
    float a0 = 0.f, a1 = 0.f, a2 = 0.f, a3 = 0.f;
    if (s0 >= 0) {
      u16x4 v = *(const u16x4*)((const unsigned short*)eo + (size_t)s0 * HD + tid * 4);
      a0 += p.x * bf2f(v[0]); a1 += p.x * bf2f(v[1]);
      a2 += p.x * bf2f(v[2]); a3 += p.x * bf2f(v[3]);
    }
    if (s1 >= 0) {
      u16x4 v = *(const u16x4*)((const unsigned short*)eo + (size_t)s1 * HD + tid * 4);
      a0 += p.y * bf2f(v[0]); a1 += p.y * bf2f(v[1]);
      a2 += p.y * bf2f(v[2]); a3 += p.y * bf2f(v[3]);
    }
    float4 res = make_float4(a0, a1, a2, a3);
    *(float4*)(out + (size_t)t * HD + tid * 4) = res;
  }
}

extern "C" void kernel_launch(void* const* d_in, const int* in_sizes, int n_in,
                              void* d_out, int out_size, void* d_ws, size_t ws_size,
                              hipStream_t stream) {
  const float* x = (const float*)d_in[0];
  const float* gw = (const float*)d_in[1];
  const float* ew = (const float*)d_in[2];
  float* out = (float*)d_out;

  char* p = (char*)d_ws;
  float* logits = (float*)p;            p += (size_t)NTOK * NE * 4;
  int2* e01 = (int2*)p;                 p += (size_t)NTOK * 8;
  float2* p01 = (float2*)p;             p += (size_t)NTOK * 8;
  int* slot_of = (int*)p;               p += (size_t)NKF * 4;
  int* slot_token = (int*)p;            p += (size_t)NSLOT * 4;
  int* counts = (int*)p;                p += 256;
  float* imp_part = (float*)p;          p += (size_t)512 * 64 * 4;
  int* rank_buf = (int*)p;              p += (size_t)NKF * 4;
  int* hist = (int*)p;                  p += (size_t)NTILE * 64 * 4;
  __hip_bfloat16* xb = (__hip_bfloat16*)p; p += (size_t)NTOK * HD * 2;
  __hip_bfloat16* Wb = (__hip_bfloat16*)p;  p += (size_t)NE * HD * HD * 2;
  __hip_bfloat16* Eo = (__hip_bfloat16*)p;  p += (size_t)NSLOT * HD * 2;

  gating_kernel<<<NTOK / 256, 512, 0, stream>>>(x, gw, logits, xb, ew, Wb);
  topk_hist_kernel<<<NTOK / 256, 256, 0, stream>>>(logits, e01, p01, imp_part, rank_buf, hist);
  place_kernel<<<NTILE, 512, 0, stream>>>(e01, rank_buf, hist, imp_part, slot_of, slot_token, counts, out);
  moe_gemm_kernel<<<dim3(1280), 512, 0, stream>>>(xb, slot_token, Wb, counts, Eo);
  combine_kernel<<<2048, 256, 0, stream>>>(Eo, slot_of, p01, out);
}

// Round 19
// 410.084 us; speedup vs baseline: 1.1742x; 1.1742x over previous
//
#include <hip/hip_runtime.h>
#include <hip/hip_bf16.h>

#define NTOK 32768
#define NE 64
#define HD 1024
#define CAP 1280
#define NKF (NTOK*2)      // 65536 flat (token,k)
#define NSLOT (NE*CAP)    // 81920
#define NTILE 128         // dispatch tiles of 512 items (256 tokens)

typedef __attribute__((ext_vector_type(8))) short bf16x8;
typedef __attribute__((ext_vector_type(4))) short bf16x4;
typedef __attribute__((ext_vector_type(4))) float f32x4;
typedef __attribute__((ext_vector_type(4))) unsigned short u16x4;

// zero A-row page: .bss (zeroed at module load, never written)
__device__ __hip_bfloat16 g_zero[1152];

__device__ __forceinline__ short f2bf(float f) {
  union { __hip_bfloat16 b; short s; } u;
  u.b = __float2bfloat16(f);
  return u.s;
}
__device__ __forceinline__ float bf2f(unsigned short h) {
  return __uint_as_float(((unsigned)h) << 16);
}

// ---- gating: logits[N,64] = x @ gw^T (fp32, verified) + emit bf16 xb, convw INTERLEAVED ----
// R16-verified: 512 blocks x 256 threads (2 blocks/CU on all 256 CUs), 64 tokens/block,
// convw load/store batches interleaved inside the K-loop so HBM traffic overlaps the
// LDS/VALU-bound FMA phases.
__global__ __launch_bounds__(256) void gating_kernel(const float* __restrict__ x,
                                                     const float* __restrict__ gw,
                                                     float* __restrict__ logits,
                                                     __hip_bfloat16* __restrict__ xb,
                                                     const float* __restrict__ ew,
                                                     __hip_bfloat16* __restrict__ wb) {
  __shared__ float Xs[64][132];
  __shared__ float Gs[64][132];
  const int tid = threadIdx.x;
  const int tok0 = blockIdx.x * 64;
  const int th = tid >> 4;
  const int te = tid & 15;
  float acc[4][4];
#pragma unroll
  for (int i = 0; i < 4; ++i)
#pragma unroll
    for (int j = 0; j < 4; ++j) acc[i][j] = 0.f;

  size_t ci = ((size_t)blockIdx.x * 256 + tid) * 8;
  const size_t cstride = (size_t)512 * 256 * 8;

  for (int k0i = 0; k0i < 8; ++k0i) {
    const int k0 = k0i * 128;
#pragma unroll
    for (int r = 0; r < 8; ++r) {
      int idx = r * 256 + tid;
      int row = idx >> 5;
      int c = (idx & 31) * 4;
      float4 xv4 = *(const float4*)&x[(size_t)(tok0 + row) * HD + k0 + c];
      *(float4*)&Xs[row][c] = xv4;
      bf16x4 o;
      o[0] = f2bf(xv4.x); o[1] = f2bf(xv4.y); o[2] = f2bf(xv4.z); o[3] = f2bf(xv4.w);
      *(bf16x4*)&xb[(size_t)(tok0 + row) * HD + k0 + c] = o;
      *(float4*)&Gs[row][c] = *(const float4*)&gw[(size_t)row * HD + k0 + c];
    }
    float4 ca[4], cb[4];
#pragma unroll
    for (int q = 0; q < 4; ++q) {
      ca[q] = *(const float4*)(ew + ci + (size_t)q * cstride);
      cb[q] = *(const float4*)(ew + ci + (size_t)q * cstride + 4);
    }
    __syncthreads();
#pragma unroll 4
    for (int kk = 0; kk < 16; ++kk) {
      float4 xv[4], gv[4];
#pragma unroll
      for (int i = 0; i < 4; ++i) xv[i] = *(float4*)&Xs[th + i * 16][kk * 4];
#pragma unroll
      for (int j = 0; j < 4; ++j) gv[j] = *(float4*)&Gs[te + j * 16][kk * 4];
#pragma unroll
      for (int i = 0; i < 4; ++i)
#pragma unroll
        for (int j = 0; j < 4; ++j) {
          acc[i][j] = fmaf(xv[i].x, gv[j].x, acc[i][j]);
          acc[i][j] = fmaf(xv[i].y, gv[j].y, acc[i][j]);
          acc[i][j] = fmaf(xv[i].z, gv[j].z, acc[i][j]);
          acc[i][j] = fmaf(xv[i].w, gv[j].w, acc[i][j]);
        }
    }
#pragma unroll
    for (int q = 0; q < 4; ++q) {
      bf16x8 o;
      o[0] = f2bf(ca[q].x); o[1] = f2bf(ca[q].y); o[2] = f2bf(ca[q].z); o[3] = f2bf(ca[q].w);
      o[4] = f2bf(cb[q].x); o[5] = f2bf(cb[q].y); o[6] = f2bf(cb[q].z); o[7] = f2bf(cb[q].w);
      *(bf16x8*)(wb + ci + (size_t)q * cstride) = o;
    }
#pragma unroll
    for (int q = 0; q < 4; ++q) {
      ca[q] = *(const float4*)(ew + ci + (size_t)(q + 4) * cstride);
      cb[q] = *(const float4*)(ew + ci + (size_t)(q + 4) * cstride + 4);
    }
#pragma unroll 4
    for (int kk = 16; kk < 32; ++kk) {
      float4 xv[4], gv[4];
#pragma unroll
      for (int i = 0; i < 4; ++i) xv[i] = *(float4*)&Xs[th + i * 16][kk * 4];
#pragma unroll
      for (int j = 0; j < 4; ++j) gv[j] = *(float4*)&Gs[te + j * 16][kk * 4];
#pragma unroll
      for (int i = 0; i < 4; ++i)
#pragma unroll
        for (int j = 0; j < 4; ++j) {
          acc[i][j] = fmaf(xv[i].x, gv[j].x, acc[i][j]);
          acc[i][j] = fmaf(xv[i].y, gv[j].y, acc[i][j]);
          acc[i][j] = fmaf(xv[i].z, gv[j].z, acc[i][j]);
          acc[i][j] = fmaf(xv[i].w, gv[j].w, acc[i][j]);
        }
    }
#pragma unroll
    for (int q = 0; q < 4; ++q) {
      bf16x8 o;
      o[0] = f2bf(ca[q].x); o[1] = f2bf(ca[q].y); o[2] = f2bf(ca[q].z); o[3] = f2bf(ca[q].w);
      o[4] = f2bf(cb[q].x); o[5] = f2bf(cb[q].y); o[6] = f2bf(cb[q].z); o[7] = f2bf(cb[q].w);
      *(bf16x8*)(wb + ci + (size_t)(q + 4) * cstride) = o;
    }
    ci += (size_t)8 * cstride;
    __syncthreads();
  }
#pragma unroll
  for (int i = 0; i < 4; ++i)
#pragma unroll
    for (int j = 0; j < 4; ++j)
      logits[(size_t)(tok0 + th + i * 16) * NE + te + j * 16] = acc[i][j];
}

// ------- fused top-2 + probs + importance + per-tile stable rank + histogram -------
__global__ __launch_bounds__(256) void topk_hist_kernel(const float* __restrict__ logits,
                                                        int2* __restrict__ e01,
                                                        float2* __restrict__ p01,
                                                        float* __restrict__ imp_part,
                                                        int* __restrict__ rank_buf,
                                                        int* __restrict__ hist) {
  __shared__ int wh[4][64];
  const int tid = threadIdx.x;
  const int w = tid >> 6, lane = tid & 63;
  const int t = blockIdx.x * 256 + tid;
  float l[64];
  const float4* lp = (const float4*)(logits + (size_t)t * NE);
#pragma unroll
  for (int i = 0; i < 16; ++i) {
    float4 v = lp[i];
    l[4 * i] = v.x; l[4 * i + 1] = v.y; l[4 * i + 2] = v.z; l[4 * i + 3] = v.w;
  }
  float v1 = -1e30f; int i1 = 0;
#pragma unroll
  for (int j = 0; j < 64; ++j) if (l[j] > v1) { v1 = l[j]; i1 = j; }
  float v2 = -1e30f; int i2 = 0;
#pragma unroll
  for (int j = 0; j < 64; ++j) if (j != i1 && l[j] > v2) { v2 = l[j]; i2 = j; }
  float ex = __expf(v2 - v1);
  float inv2 = 1.f / (1.f + ex);
  e01[t] = make_int2(i1, i2);
  p01[t] = make_float2(inv2, ex * inv2);

  float s = 0.f;
#pragma unroll
  for (int j = 0; j < 64; ++j) s += __expf(l[j] - v1);
  float invs = 1.f / s;
  const int wid = t >> 6;
#pragma unroll
  for (int e = 0; e < 64; ++e) {
    float p = __expf(l[e] - v1) * invs;
#pragma unroll
    for (int off = 32; off; off >>= 1) p += __shfl_xor(p, off);
    if (lane == 0) imp_part[(size_t)wid * 64 + e] = p;
  }

  int r0 = 0, r1 = 0, cnt = 0;
#pragma unroll
  for (int j = 0; j < 64; ++j) {
    int a = __shfl(i1, j);
    int b = __shfl(i2, j);
    int ja = (j < lane);
    r0 += ja & (a == i1);
    r0 += ja & (b == i1);
    r1 += ja & (a == i2);
    r1 += ja & (b == i2);
    cnt += (a == lane) + (b == lane);
  }
  wh[w][lane] = cnt;
  __syncthreads();
#pragma unroll
  for (int ww = 0; ww < 4; ++ww)
    if (ww < w) { r0 += wh[ww][i1]; r1 += wh[ww][i2]; }
  rank_buf[2 * t] = r0;
  rank_buf[2 * t + 1] = r1;
  if (tid < 64)
    hist[blockIdx.x * 64 + tid] = wh[0][tid] + wh[1][tid] + wh[2][tid] + wh[3][tid];
}

// ------- dispatch: per-expert exclusive scan over tiles + aux loss (folded) -------
__global__ __launch_bounds__(64) void scan_aux_kernel(const int* __restrict__ hist,
                                                      const float* __restrict__ imp_part,
                                                      int* __restrict__ tile_off,
                                                      int* __restrict__ counts,
                                                      float* __restrict__ out) {
  const int e = threadIdx.x;
  int run = 0;
  for (int t = 0; t < NTILE; ++t) {
    int h = hist[t * 64 + e];
    tile_off[t * 64 + e] = run;
    run += h;
  }
  counts[e] = run;

  float imp = 0.f;
  for (int w = 0; w < 512; ++w) imp += imp_part[(size_t)w * 64 + e];
  imp *= (1.f / (float)NTOK);
  float usage = (float)run / (float)NKF;
  float v = usage * imp;
#pragma unroll
  for (int off = 32; off; off >>= 1) v += __shfl_xor(v, off);
  if (e == 0) out[(size_t)NTOK * HD] = fminf(v * (float)NE * 0.01f, 1.0f);
}

// ------- dispatch: place -------
__global__ __launch_bounds__(256) void place_kernel(const int2* __restrict__ e01,
                                                    const int* __restrict__ rank_buf,
                                                    const int* __restrict__ tile_off,
                                                    int* __restrict__ slot_of,
                                                    int* __restrict__ slot_token) {
  const int tid = threadIdx.x;
  const int i = blockIdx.x * 256 + tid;
  int2 ee = e01[i >> 1];
  const int e = (i & 1) ? ee.y : ee.x;
  const int pos = tile_off[(i >> 9) * 64 + e] + rank_buf[i];
  const int slot = (pos < CAP) ? (e * CAP + pos) : -1;
  slot_of[i] = slot;
  if (slot >= 0) slot_token[slot] = i;
}

// -------- grouped expert GEMM: 256x256, BK=64, 8-wave, fused A-gather, 3-buf B ring --------
#define ASYNC16(g, l) __builtin_amdgcn_global_load_lds( \
    (const __attribute__((address_space(1))) void*)(g), \
    (__attribute__((address_space(3))) void*)(l), 16, 0, 0)

#define STAGE_A(buf, ks, kcol) do {                                             \
    const int _d = ((buf) * 16384 + (ks) * 8192 + wuni) * 2;                    \
    ASYNC16(arow0 + (kcol) + (ks) * 32 + sw8, (char*)lds + _d);                 \
    ASYNC16(arow1 + (kcol) + (ks) * 32 + sw8, (char*)lds + _d + 8192);          \
  } while (0)

#define STAGE_B3(buf3, ks, kcol) do {                                           \
    const __hip_bfloat16* _g = B + (size_t)srow * HD + (kcol) + (ks) * 32 + sw8; \
    const int _d = (32768 + (buf3) * 16384 + (ks) * 8192 + wuni) * 2;           \
    ASYNC16(_g, (char*)lds + _d);                                               \
    ASYNC16(_g + (size_t)128 * HD, (char*)lds + _d + 8192);                     \
  } while (0)

#define LDA(dst, buf, ks, mi) \
  dst = *(const bf16x8*)(lds + (buf) * 16384 + (ks) * 8192 + (wm * 128 + (mi) * 16 + fr) * 32 + rsw)
#define LDB3(dst, buf3, ks, ni) \
  dst = *(const bf16x8*)(lds + 32768 + (buf3) * 16384 + (ks) * 8192 + (wn * 64 + (ni) * 16 + fr) * 32 + rsw)

#define MFMA_HALF(h)                                                            \
  _Pragma("unroll")                                                             \
  for (int mm = 0; mm < 4; ++mm)                                                \
    _Pragma("unroll")                                                           \
    for (int nn = 0; nn < 4; ++nn)                                              \
      acc[(h) * 4 + mm][nn] =                                                   \
          __builtin_amdgcn_mfma_f32_16x16x32_bf16(av[mm], bv[nn], acc[(h) * 4 + mm][nn], 0, 0, 0)

#define BARX() do { asm volatile("" ::: "memory"); __builtin_amdgcn_s_barrier(); asm volatile("" ::: "memory"); } while (0)
#define VMC(n) asm volatile("s_waitcnt vmcnt(" #n ")" ::: "memory")

__global__ __launch_bounds__(512, 2) void moe_gemm_kernel(const __hip_bfloat16* __restrict__ xb,
                                                          const int* __restrict__ slot_token,
                                                          const __hip_bfloat16* __restrict__ Wb,
                                                          const int* __restrict__ counts,
                                                          __hip_bfloat16* __restrict__ Eo) {
  __shared__ __hip_bfloat16 lds[81920];  // 160 KB exactly

  const int bid = blockIdx.x;
  const int swz = (bid & 7) * 160 + (bid >> 3);
  const int e = swz / 20;
  const int t20 = swz - e * 20;
  const int tm = t20 >> 2, tn = t20 & 3;

  const int cnt = counts[e];
  if (tm * 256 >= cnt) return;  // capacity-tile skip

  const int tid = threadIdx.x;
  const int lane = tid & 63;
  const int w = tid >> 6;
  const int wm = w >> 2, wn = w & 3;

  const __hip_bfloat16* B = Wb + (size_t)e * HD * HD + (size_t)(tn * 256) * HD;

  const int srow = tid >> 2;
  const int sw8 = ((tid & 3) ^ ((tid >> 3) & 3)) * 8;
  const int wuni = w * 512;

  const int slotbase = e * CAP + tm * 256;
  const int r0row = tm * 256 + srow;
  const int i0 = slot_token[slotbase + srow];
  const int i1 = slot_token[slotbase + 128 + srow];
  const __hip_bfloat16* arow0 = (r0row < cnt) ? xb + (size_t)(i0 >> 1) * HD : g_zero;
  const __hip_bfloat16* arow1 = (r0row + 128 < cnt) ? xb + (size_t)(i1 >> 1) * HD : g_zero;

  const int fr = lane & 15;
  const int fq = lane >> 4;
  const int rsw = (fq ^ ((fr >> 1) & 3)) * 8;

  f32x4 acc[8][4] = {};

  STAGE_A(0, 0, 0);
  STAGE_A(0, 1, 0);
  STAGE_B3(0, 0, 0);
  STAGE_B3(0, 1, 0);
  STAGE_B3(1, 0, 64);
  STAGE_B3(1, 1, 64);
  VMC(4);
  BARX();

#pragma unroll 2
  for (int t = 0; t < 16; ++t) {
    const int ard = t & 1, ast = ard ^ 1;
    const int b_rd = t % 3;
    int b_st = b_rd + 2; if (b_st >= 3) b_st -= 3;
    const int kcA = (t + 1) * 64;
    const int kcB = (t + 2) * 64;
    const bool hA = (t < 15);
    const bool hB = (t < 14);
    bf16x8 av[4], bv[4];

    LDB3(bv[0], b_rd, 0, 0); LDB3(bv[1], b_rd, 0, 1); LDB3(bv[2], b_rd, 0, 2); LDB3(bv[3], b_rd, 0, 3);
    LDA(av[0], ard, 0, 0); LDA(av[1], ard, 0, 1); LDA(av[2], ard, 0, 2); LDA(av[3], ard, 0, 3);
    if (hA) STAGE_A(ast, 0, kcA);
    BARX();
    __builtin_amdgcn_s_setprio(1);
    MFMA_HALF(0);
    __builtin_amdgcn_s_setprio(0);
    BARX();

    LDA(av[0], ard, 0, 4); LDA(av[1], ard, 0, 5); LDA(av[2], ard, 0, 6); LDA(av[3], ard, 0, 7);
    if (hB) {
      STAGE_B3(b_st, 0, kcB);
      VMC(6);
    } else if (t == 14) {
      VMC(4);
    } else {
      VMC(0);
    }
    BARX();
    __builtin_amdgcn_s_setprio(1);
    MFMA_HALF(1);
    __builtin_amdgcn_s_setprio(0);
    BARX();

    LDB3(bv[0], b_rd, 1, 0); LDB3(bv[1], b_rd, 1, 1); LDB3(bv[2], b_rd, 1, 2); LDB3(bv[3], b_rd, 1, 3);
    LDA(av[0], ard, 1, 0); LDA(av[1], ard, 1, 1); LDA(av[2], ard, 1, 2); LDA(av[3], ard, 1, 3);
    if (hA) STAGE_A(ast, 1, kcA);
    BARX();
    __builtin_amdgcn_s_setprio(1);
    MFMA_HALF(0);
    __builtin_amdgcn_s_setprio(0);
    BARX();

    LDA(av[0], ard, 1, 4); LDA(av[1], ard, 1, 5); LDA(av[2], ard, 1, 6); LDA(av[3], ard, 1, 7);
    if (hB) {
      STAGE_B3(b_st, 1, kcB);
      VMC(6);
    } else if (t == 14) {
      VMC(2);
    }
    BARX();
    __builtin_amdgcn_s_setprio(1);
    MFMA_HALF(1);
    __builtin_amdgcn_s_setprio(0);
    BARX();
  }

  __hip_bfloat16* C = Eo + (size_t)e * CAP * HD +
                      (size_t)(tm * 256 + wm * 128) * HD + tn * 256 + wn * 64;
#pragma unroll
  for (int m = 0; m < 8; ++m)
#pragma unroll
    for (int n = 0; n < 4; ++n)
#pragma unroll
      for (int r = 0; r < 4; ++r)
        C[(size_t)(m * 16 + fq * 4 + r) * HD + n * 16 + fr] = __float2bfloat16(acc[m][n][r]);
}

// ---------------- combine ----------------
__global__ __launch_bounds__(256) void combine_kernel(const __hip_bfloat16* __restrict__ eo,
                                                      const int* __restrict__ slot_of,
                                                      const float2* __restrict__ p01,
                                                      float* __restrict__ out) {
  const int t = blockIdx.x;
  const int tid = threadIdx.x;
  const float2 p = p01[t];
  const int s0 = slot_of[2 * t], s1 = slot_of[2 * t + 1];
  float a0 = 0.f, a1 = 0.f, a2 = 0.f, a3 = 0.f;
  if (s0 >= 0) {
    u16x4 v = *(const u16x4*)((const unsigned short*)eo + (size_t)s0 * HD + tid * 4);
    a0 += p.x * bf2f(v[0]); a1 += p.x * bf2f(v[1]);
    a2 += p.x * bf2f(v[2]); a3 += p.x * bf2f(v[3]);
  }
  if (s1 >= 0) {
    u16x4 v = *(const u16x4*)((const unsigned short*)eo + (size_t)s1 * HD + tid * 4);
    a0 += p.y * bf2f(v[0]); a1 += p.y * bf2f(v[1]);
    a2 += p.y * bf2f(v[2]); a3 += p.y * bf2f(v[3]);
  }
  float4 res = make_float4(a0, a1, a2, a3);
  *(float4*)(out + (size_t)t * HD + tid * 4) = res;
}

extern "C" void kernel_launch(void* const* d_in, const int* in_sizes, int n_in,
                              void* d_out, int out_size, void* d_ws, size_t ws_size,
                              hipStream_t stream) {
  const float* x = (const float*)d_in[0];
  const float* gw = (const float*)d_in[1];
  const float* ew = (const float*)d_in[2];
  float* out = (float*)d_out;

  char* p = (char*)d_ws;
  float* logits = (float*)p;            p += (size_t)NTOK * NE * 4;
  int2* e01 = (int2*)p;                 p += (size_t)NTOK * 8;
  float2* p01 = (float2*)p;             p += (size_t)NTOK * 8;
  int* slot_of = (int*)p;               p += (size_t)NKF * 4;
  int* slot_token = (int*)p;            p += (size_t)NSLOT * 4;
  int* counts = (int*)p;                p += 256;
  float* imp_part = (float*)p;          p += (size_t)512 * 64 * 4;
  int* rank_buf = (int*)p;              p += (size_t)NKF * 4;
  int* hist = (int*)p;                  p += (size_t)NTILE * 64 * 4;
  int* tile_off = (int*)p;              p += (size_t)NTILE * 64 * 4;
  __hip_bfloat16* xb = (__hip_bfloat16*)p; p += (size_t)NTOK * HD * 2;
  __hip_bfloat16* Wb = (__hip_bfloat16*)p;  p += (size_t)NE * HD * HD * 2;
  __hip_bfloat16* Eo = (__hip_bfloat16*)p;  p += (size_t)NSLOT * HD * 2;

  gating_kernel<<<NTOK / 64, 256, 0, stream>>>(x, gw, logits, xb, ew, Wb);
  topk_hist_kernel<<<NTOK / 256, 256, 0, stream>>>(logits, e01, p01, imp_part, rank_buf, hist);
  scan_aux_kernel<<<1, 64, 0, stream>>>(hist, imp_part, tile_off, counts, out);
  place_kernel<<<NKF / 256, 256, 0, stream>>>(e01, rank_buf, tile_off, slot_of, slot_token);
  moe_gemm_kernel<<<dim3(1280), 512, 0, stream>>>(xb, slot_token, Wb, counts, Eo);
  combine_kernel<<<NTOK, 256, 0, stream>>>(Eo, slot_of, p01, out);
}

// Round 20
// 405.525 us; speedup vs baseline: 1.1874x; 1.0112x over previous
//
#include <hip/hip_runtime.h>
#include <hip/hip_bf16.h>

#define NTOK 32768
#define NE 64
#define HD 1024
#define CAP 1280
#define NKF (NTOK*2)      // 65536 flat (token,k)
#define NSLOT (NE*CAP)    // 81920
#define NTILE 128         // dispatch tiles of 512 items (256 tokens)

typedef __attribute__((ext_vector_type(8))) short bf16x8;
typedef __attribute__((ext_vector_type(4))) short bf16x4;
typedef __attribute__((ext_vector_type(4))) float f32x4;
typedef __attribute__((ext_vector_type(4))) unsigned short u16x4;

// zero A-row page: .bss (zeroed at module load, never written)
__device__ __hip_bfloat16 g_zero[1152];

__device__ __forceinline__ short f2bf(float f) {
  union { __hip_bfloat16 b; short s; } u;
  u.b = __float2bfloat16(f);
  return u.s;
}
__device__ __forceinline__ float bf2f(unsigned short h) {
  return __uint_as_float(((unsigned)h) << 16);
}

// ---- gating: logits[N,64] = x @ gw^T (fp32) + emit bf16 xb, convw INTERLEAVED ----
// K-chunk 64 (33.8 KB LDS) -> 4 blocks/CU = 16 waves/CU (2x the TLP of chunk-128) to
// overlap staging-HBM / FMA-LDS / convw-HBM phases. Per-logit FMA order is strictly
// k-ascending (chunk-major, kk, xyzw) -> bit-identical logits to the verified config.
__global__ __launch_bounds__(256, 4) void gating_kernel(const float* __restrict__ x,
                                                        const float* __restrict__ gw,
                                                        float* __restrict__ logits,
                                                        __hip_bfloat16* __restrict__ xb,
                                                        const float* __restrict__ ew,
                                                        __hip_bfloat16* __restrict__ wb) {
  __shared__ float Xs[64][66];
  __shared__ float Gs[64][66];
  const int tid = threadIdx.x;
  const int tok0 = blockIdx.x * 64;
  const int th = tid >> 4;   // token sub-row 0..15
  const int te = tid & 15;   // expert sub-col 0..15
  float acc[4][4];
#pragma unroll
  for (int i = 0; i < 4; ++i)
#pragma unroll
    for (int j = 0; j < 4; ++j) acc[i][j] = 0.f;

  // convw: 67.1M floats / (512 blk * 256 th * 8 per step) = 64 steps; 4 per chunk
  size_t ci = ((size_t)blockIdx.x * 256 + tid) * 8;
  const size_t cstride = (size_t)512 * 256 * 8;

  for (int k0i = 0; k0i < 16; ++k0i) {
    const int k0 = k0i * 64;
    // stage x tile (64 rows x 64 k) + emit xb; stage gw tile
#pragma unroll
    for (int r = 0; r < 4; ++r) {
      int idx = r * 256 + tid;
      int row = idx >> 4;
      int c = (idx & 15) * 4;
      float4 xv4 = *(const float4*)&x[(size_t)(tok0 + row) * HD + k0 + c];
      *(float4*)&Xs[row][c] = xv4;
      bf16x4 o;
      o[0] = f2bf(xv4.x); o[1] = f2bf(xv4.y); o[2] = f2bf(xv4.z); o[3] = f2bf(xv4.w);
      *(bf16x4*)&xb[(size_t)(tok0 + row) * HD + k0 + c] = o;
      *(float4*)&Gs[row][c] = *(const float4*)&gw[(size_t)row * HD + k0 + c];
    }
    // issue convw batch 0 (2 steps)
    float4 ca[2], cb[2];
#pragma unroll
    for (int q = 0; q < 2; ++q) {
      ca[q] = *(const float4*)(ew + ci + (size_t)q * cstride);
      cb[q] = *(const float4*)(ew + ci + (size_t)q * cstride + 4);
    }
    __syncthreads();
#pragma unroll 4
    for (int kk = 0; kk < 8; ++kk) {
      float4 xv[4], gv[4];
#pragma unroll
      for (int i = 0; i < 4; ++i) xv[i] = *(float4*)&Xs[th + i * 16][kk * 4];
#pragma unroll
      for (int j = 0; j < 4; ++j) gv[j] = *(float4*)&Gs[te + j * 16][kk * 4];
#pragma unroll
      for (int i = 0; i < 4; ++i)
#pragma unroll
        for (int j = 0; j < 4; ++j) {
          acc[i][j] = fmaf(xv[i].x, gv[j].x, acc[i][j]);
          acc[i][j] = fmaf(xv[i].y, gv[j].y, acc[i][j]);
          acc[i][j] = fmaf(xv[i].z, gv[j].z, acc[i][j]);
          acc[i][j] = fmaf(xv[i].w, gv[j].w, acc[i][j]);
        }
    }
    // store batch 0, issue batch 1
#pragma unroll
    for (int q = 0; q < 2; ++q) {
      bf16x8 o;
      o[0] = f2bf(ca[q].x); o[1] = f2bf(ca[q].y); o[2] = f2bf(ca[q].z); o[3] = f2bf(ca[q].w);
      o[4] = f2bf(cb[q].x); o[5] = f2bf(cb[q].y); o[6] = f2bf(cb[q].z); o[7] = f2bf(cb[q].w);
      *(bf16x8*)(wb + ci + (size_t)q * cstride) = o;
    }
#pragma unroll
    for (int q = 0; q < 2; ++q) {
      ca[q] = *(const float4*)(ew + ci + (size_t)(q + 2) * cstride);
      cb[q] = *(const float4*)(ew + ci + (size_t)(q + 2) * cstride + 4);
    }
#pragma unroll 4
    for (int kk = 8; kk < 16; ++kk) {
      float4 xv[4], gv[4];
#pragma unroll
      for (int i = 0; i < 4; ++i) xv[i] = *(float4*)&Xs[th + i * 16][kk * 4];
#pragma unroll
      for (int j = 0; j < 4; ++j) gv[j] = *(float4*)&Gs[te + j * 16][kk * 4];
#pragma unroll
      for (int i = 0; i < 4; ++i)
#pragma unroll
        for (int j = 0; j < 4; ++j) {
          acc[i][j] = fmaf(xv[i].x, gv[j].x, acc[i][j]);
          acc[i][j] = fmaf(xv[i].y, gv[j].y, acc[i][j]);
          acc[i][j] = fmaf(xv[i].z, gv[j].z, acc[i][j]);
          acc[i][j] = fmaf(xv[i].w, gv[j].w, acc[i][j]);
        }
    }
#pragma unroll
    for (int q = 0; q < 2; ++q) {
      bf16x8 o;
      o[0] = f2bf(ca[q].x); o[1] = f2bf(ca[q].y); o[2] = f2bf(ca[q].z); o[3] = f2bf(ca[q].w);
      o[4] = f2bf(cb[q].x); o[5] = f2bf(cb[q].y); o[6] = f2bf(cb[q].z); o[7] = f2bf(cb[q].w);
      *(bf16x8*)(wb + ci + (size_t)(q + 2) * cstride) = o;
    }
    ci += (size_t)4 * cstride;
    __syncthreads();
  }
#pragma unroll
  for (int i = 0; i < 4; ++i)
#pragma unroll
    for (int j = 0; j < 4; ++j)
      logits[(size_t)(tok0 + th + i * 16) * NE + te + j * 16] = acc[i][j];
}

// ------- fused top-2 + probs + importance + per-tile stable rank + histogram -------
__global__ __launch_bounds__(256) void topk_hist_kernel(const float* __restrict__ logits,
                                                        int2* __restrict__ e01,
                                                        float2* __restrict__ p01,
                                                        float* __restrict__ imp_part,
                                                        int* __restrict__ rank_buf,
                                                        int* __restrict__ hist) {
  __shared__ int wh[4][64];
  const int tid = threadIdx.x;
  const int w = tid >> 6, lane = tid & 63;
  const int t = blockIdx.x * 256 + tid;
  float l[64];
  const float4* lp = (const float4*)(logits + (size_t)t * NE);
#pragma unroll
  for (int i = 0; i < 16; ++i) {
    float4 v = lp[i];
    l[4 * i] = v.x; l[4 * i + 1] = v.y; l[4 * i + 2] = v.z; l[4 * i + 3] = v.w;
  }
  float v1 = -1e30f; int i1 = 0;
#pragma unroll
  for (int j = 0; j < 64; ++j) if (l[j] > v1) { v1 = l[j]; i1 = j; }
  float v2 = -1e30f; int i2 = 0;
#pragma unroll
  for (int j = 0; j < 64; ++j) if (j != i1 && l[j] > v2) { v2 = l[j]; i2 = j; }
  float ex = __expf(v2 - v1);
  float inv2 = 1.f / (1.f + ex);
  e01[t] = make_int2(i1, i2);
  p01[t] = make_float2(inv2, ex * inv2);

  float s = 0.f;
#pragma unroll
  for (int j = 0; j < 64; ++j) s += __expf(l[j] - v1);
  float invs = 1.f / s;
  const int wid = t >> 6;
#pragma unroll
  for (int e = 0; e < 64; ++e) {
    float p = __expf(l[e] - v1) * invs;
#pragma unroll
    for (int off = 32; off; off >>= 1) p += __shfl_xor(p, off);
    if (lane == 0) imp_part[(size_t)wid * 64 + e] = p;
  }

  int r0 = 0, r1 = 0, cnt = 0;
#pragma unroll
  for (int j = 0; j < 64; ++j) {
    int a = __shfl(i1, j);
    int b = __shfl(i2, j);
    int ja = (j < lane);
    r0 += ja & (a == i1);
    r0 += ja & (b == i1);
    r1 += ja & (a == i2);
    r1 += ja & (b == i2);
    cnt += (a == lane) + (b == lane);
  }
  wh[w][lane] = cnt;
  __syncthreads();
#pragma unroll
  for (int ww = 0; ww < 4; ++ww)
    if (ww < w) { r0 += wh[ww][i1]; r1 += wh[ww][i2]; }
  rank_buf[2 * t] = r0;
  rank_buf[2 * t + 1] = r1;
  if (tid < 64)
    hist[blockIdx.x * 64 + tid] = wh[0][tid] + wh[1][tid] + wh[2][tid] + wh[3][tid];
}

// ------- dispatch: per-expert exclusive scan over tiles + aux loss (folded) -------
__global__ __launch_bounds__(64) void scan_aux_kernel(const int* __restrict__ hist,
                                                      const float* __restrict__ imp_part,
                                                      int* __restrict__ tile_off,
                                                      int* __restrict__ counts,
                                                      float* __restrict__ out) {
  const int e = threadIdx.x;
  int run = 0;
  for (int t = 0; t < NTILE; ++t) {
    int h = hist[t * 64 + e];
    tile_off[t * 64 + e] = run;
    run += h;
  }
  counts[e] = run;

  float imp = 0.f;
  for (int w = 0; w < 512; ++w) imp += imp_part[(size_t)w * 64 + e];
  imp *= (1.f / (float)NTOK);
  float usage = (float)run / (float)NKF;
  float v = usage * imp;
#pragma unroll
  for (int off = 32; off; off >>= 1) v += __shfl_xor(v, off);
  if (e == 0) out[(size_t)NTOK * HD] = fminf(v * (float)NE * 0.01f, 1.0f);
}

// ------- dispatch: place -------
__global__ __launch_bounds__(256) void place_kernel(const int2* __restrict__ e01,
                                                    const int* __restrict__ rank_buf,
                                                    const int* __restrict__ tile_off,
                                                    int* __restrict__ slot_of,
                                                    int* __restrict__ slot_token) {
  const int tid = threadIdx.x;
  const int i = blockIdx.x * 256 + tid;
  int2 ee = e01[i >> 1];
  const int e = (i & 1) ? ee.y : ee.x;
  const int pos = tile_off[(i >> 9) * 64 + e] + rank_buf[i];
  const int slot = (pos < CAP) ? (e * CAP + pos) : -1;
  slot_of[i] = slot;
  if (slot >= 0) slot_token[slot] = i;
}

// -------- grouped expert GEMM: 256x256, BK=64, 8-wave, fused A-gather, 3-buf B ring --------
#define ASYNC16(g, l) __builtin_amdgcn_global_load_lds( \
    (const __attribute__((address_space(1))) void*)(g), \
    (__attribute__((address_space(3))) void*)(l), 16, 0, 0)

#define STAGE_A(buf, ks, kcol) do {                                             \
    const int _d = ((buf) * 16384 + (ks) * 8192 + wuni) * 2;                    \
    ASYNC16(arow0 + (kcol) + (ks) * 32 + sw8, (char*)lds + _d);                 \
    ASYNC16(arow1 + (kcol) + (ks) * 32 + sw8, (char*)lds + _d + 8192);          \
  } while (0)

#define STAGE_B3(buf3, ks, kcol) do {                                           \
    const __hip_bfloat16* _g = B + (size_t)srow * HD + (kcol) + (ks) * 32 + sw8; \
    const int _d = (32768 + (buf3) * 16384 + (ks) * 8192 + wuni) * 2;           \
    ASYNC16(_g, (char*)lds + _d);                                               \
    ASYNC16(_g + (size_t)128 * HD, (char*)lds + _d + 8192);                     \
  } while (0)

#define LDA(dst, buf, ks, mi) \
  dst = *(const bf16x8*)(lds + (buf) * 16384 + (ks) * 8192 + (wm * 128 + (mi) * 16 + fr) * 32 + rsw)
#define LDB3(dst, buf3, ks, ni) \
  dst = *(const bf16x8*)(lds + 32768 + (buf3) * 16384 + (ks) * 8192 + (wn * 64 + (ni) * 16 + fr) * 32 + rsw)

#define MFMA_HALF(h)                                                            \
  _Pragma("unroll")                                                             \
  for (int mm = 0; mm < 4; ++mm)                                                \
    _Pragma("unroll")                                                           \
    for (int nn = 0; nn < 4; ++nn)                                              \
      acc[(h) * 4 + mm][nn] =                                                   \
          __builtin_amdgcn_mfma_f32_16x16x32_bf16(av[mm], bv[nn], acc[(h) * 4 + mm][nn], 0, 0, 0)

#define BARX() do { asm volatile("" ::: "memory"); __builtin_amdgcn_s_barrier(); asm volatile("" ::: "memory"); } while (0)
#define VMC(n) asm volatile("s_waitcnt vmcnt(" #n ")" ::: "memory")

__global__ __launch_bounds__(512, 2) void moe_gemm_kernel(const __hip_bfloat16* __restrict__ xb,
                                                          const int* __restrict__ slot_token,
                                                          const __hip_bfloat16* __restrict__ Wb,
                                                          const int* __restrict__ counts,
                                                          __hip_bfloat16* __restrict__ Eo) {
  __shared__ __hip_bfloat16 lds[81920];  // 160 KB exactly

  const int bid = blockIdx.x;
  const int swz = (bid & 7) * 160 + (bid >> 3);
  const int e = swz / 20;
  const int t20 = swz - e * 20;
  const int tm = t20 >> 2, tn = t20 & 3;

  const int cnt = counts[e];
  if (tm * 256 >= cnt) return;  // capacity-tile skip

  const int tid = threadIdx.x;
  const int lane = tid & 63;
  const int w = tid >> 6;
  const int wm = w >> 2, wn = w & 3;

  const __hip_bfloat16* B = Wb + (size_t)e * HD * HD + (size_t)(tn * 256) * HD;

  const int srow = tid >> 2;
  const int sw8 = ((tid & 3) ^ ((tid >> 3) & 3)) * 8;
  const int wuni = w * 512;

  const int slotbase = e * CAP + tm * 256;
  const int r0row = tm * 256 + srow;
  const int i0 = slot_token[slotbase + srow];
  const int i1 = slot_token[slotbase + 128 + srow];
  const __hip_bfloat16* arow0 = (r0row < cnt) ? xb + (size_t)(i0 >> 1) * HD : g_zero;
  const __hip_bfloat16* arow1 = (r0row + 128 < cnt) ? xb + (size_t)(i1 >> 1) * HD : g_zero;

  const int fr = lane & 15;
  const int fq = lane >> 4;
  const int rsw = (fq ^ ((fr >> 1) & 3)) * 8;

  f32x4 acc[8][4] = {};

  STAGE_A(0, 0, 0);
  STAGE_A(0, 1, 0);
  STAGE_B3(0, 0, 0);
  STAGE_B3(0, 1, 0);
  STAGE_B3(1, 0, 64);
  STAGE_B3(1, 1, 64);
  VMC(4);
  BARX();

#pragma unroll 2
  for (int t = 0; t < 16; ++t) {
    const int ard = t & 1, ast = ard ^ 1;
    const int b_rd = t % 3;
    int b_st = b_rd + 2; if (b_st >= 3) b_st -= 3;
    const int kcA = (t + 1) * 64;
    const int kcB = (t + 2) * 64;
    const bool hA = (t < 15);
    const bool hB = (t < 14);
    bf16x8 av[4], bv[4];

    LDB3(bv[0], b_rd, 0, 0); LDB3(bv[1], b_rd, 0, 1); LDB3(bv[2], b_rd, 0, 2); LDB3(bv[3], b_rd, 0, 3);
    LDA(av[0], ard, 0, 0); LDA(av[1], ard, 0, 1); LDA(av[2], ard, 0, 2); LDA(av[3], ard, 0, 3);
    if (hA) STAGE_A(ast, 0, kcA);
    BARX();
    __builtin_amdgcn_s_setprio(1);
    MFMA_HALF(0);
    __builtin_amdgcn_s_setprio(0);
    BARX();

    LDA(av[0], ard, 0, 4); LDA(av[1], ard, 0, 5); LDA(av[2], ard, 0, 6); LDA(av[3], ard, 0, 7);
    if (hB) {
      STAGE_B3(b_st, 0, kcB);
      VMC(6);
    } else if (t == 14) {
      VMC(4);
    } else {
      VMC(0);
    }
    BARX();
    __builtin_amdgcn_s_setprio(1);
    MFMA_HALF(1);
    __builtin_amdgcn_s_setprio(0);
    BARX();

    LDB3(bv[0], b_rd, 1, 0); LDB3(bv[1], b_rd, 1, 1); LDB3(bv[2], b_rd, 1, 2); LDB3(bv[3], b_rd, 1, 3);
    LDA(av[0], ard, 1, 0); LDA(av[1], ard, 1, 1); LDA(av[2], ard, 1, 2); LDA(av[3], ard, 1, 3);
    if (hA) STAGE_A(ast, 1, kcA);
    BARX();
    __builtin_amdgcn_s_setprio(1);
    MFMA_HALF(0);
    __builtin_amdgcn_s_setprio(0);
    BARX();

    LDA(av[0], ard, 1, 4); LDA(av[1], ard, 1, 5); LDA(av[2], ard, 1, 6); LDA(av[3], ard, 1, 7);
    if (hB) {
      STAGE_B3(b_st, 1, kcB);
      VMC(6);
    } else if (t == 14) {
      VMC(2);
    }
    BARX();
    __builtin_amdgcn_s_setprio(1);
    MFMA_HALF(1);
    __builtin_amdgcn_s_setprio(0);
    BARX();
  }

  __hip_bfloat16* C = Eo + (size_t)e * CAP * HD +
                      (size_t)(tm * 256 + wm * 128) * HD + tn * 256 + wn * 64;
#pragma unroll
  for (int m = 0; m < 8; ++m)
#pragma unroll
    for (int n = 0; n < 4; ++n)
#pragma unroll
      for (int r = 0; r < 4; ++r)
        C[(size_t)(m * 16 + fq * 4 + r) * HD + n * 16 + fr] = __float2bfloat16(acc[m][n][r]);
}

// ---------------- combine ----------------
__global__ __launch_bounds__(256) void combine_kernel(const __hip_bfloat16* __restrict__ eo,
                                                      const int* __restrict__ slot_of,
                                                      const float2* __restrict__ p01,
                                                      float* __restrict__ out) {
  const int t = blockIdx.x;
  const int tid = threadIdx.x;
  const float2 p = p01[t];
  const int s0 = slot_of[2 * t], s1 = slot_of[2 * t + 1];
  float a0 = 0.f, a1 = 0.f, a2 = 0.f, a3 = 0.f;
  if (s0 >= 0) {
    u16x4 v = *(const u16x4*)((const unsigned short*)eo + (size_t)s0 * HD + tid * 4);
    a0 += p.x * bf2f(v[0]); a1 += p.x * bf2f(v[1]);
    a2 += p.x * bf2f(v[2]); a3 += p.x * bf2f(v[3]);
  }
  if (s1 >= 0) {
    u16x4 v = *(const u16x4*)((const unsigned short*)eo + (size_t)s1 * HD + tid * 4);
    a0 += p.y * bf2f(v[0]); a1 += p.y * bf2f(v[1]);
    a2 += p.y * bf2f(v[2]); a3 += p.y * bf2f(v[3]);
  }
  float4 res = make_float4(a0, a1, a2, a3);
  *(float4*)(out + (size_t)t * HD + tid * 4) = res;
}

extern "C" void kernel_launch(void* const* d_in, const int* in_sizes, int n_in,
                              void* d_out, int out_size, void* d_ws, size_t ws_size,
                              hipStream_t stream) {
  const float* x = (const float*)d_in[0];
  const float* gw = (const float*)d_in[1];
  const float* ew = (const float*)d_in[2];
  float* out = (float*)d_out;

  char* p = (char*)d_ws;
  float* logits = (float*)p;            p += (size_t)NTOK * NE * 4;
  int2* e01 = (int2*)p;                 p += (size_t)NTOK * 8;
  float2* p01 = (float2*)p;             p += (size_t)NTOK * 8;
  int* slot_of = (int*)p;               p += (size_t)NKF * 4;
  int* slot_token = (int*)p;            p += (size_t)NSLOT * 4;
  int* counts = (int*)p;                p += 256;
  float* imp_part = (float*)p;          p += (size_t)512 * 64 * 4;
  int* rank_buf = (int*)p;              p += (size_t)NKF * 4;
  int* hist = (int*)p;                  p += (size_t)NTILE * 64 * 4;
  int* tile_off = (int*)p;              p += (size_t)NTILE * 64 * 4;
  __hip_bfloat16* xb = (__hip_bfloat16*)p; p += (size_t)NTOK * HD * 2;
  __hip_bfloat16* Wb = (__hip_bfloat16*)p;  p += (size_t)NE * HD * HD * 2;
  __hip_bfloat16* Eo = (__hip_bfloat16*)p;  p += (size_t)NSLOT * HD * 2;

  gating_kernel<<<NTOK / 64, 256, 0, stream>>>(x, gw, logits, xb, ew, Wb);
  topk_hist_kernel<<<NTOK / 256, 256, 0, stream>>>(logits, e01, p01, imp_part, rank_buf, hist);
  scan_aux_kernel<<<1, 64, 0, stream>>>(hist, imp_part, tile_off, counts, out);
  place_kernel<<<NKF / 256, 256, 0, stream>>>(e01, rank_buf, tile_off, slot_of, slot_token);
  moe_gemm_kernel<<<dim3(1280), 512, 0, stream>>>(xb, slot_token, Wb, counts, Eo);
  combine_kernel<<<NTOK, 256, 0, stream>>>(Eo, slot_of, p01, out);
}

// Round 21
// 393.050 us; speedup vs baseline: 1.2251x; 1.0317x over previous
//
#include <hip/hip_runtime.h>
#include <hip/hip_bf16.h>

#define NTOK 32768
#define NE 64
#define HD 1024
#define CAP 1280
#define NKF (NTOK*2)      // 65536 flat (token,k)
#define NSLOT (NE*CAP)    // 81920
#define NTILE 128         // dispatch tiles of 512 items (256 tokens)

typedef __attribute__((ext_vector_type(8))) short bf16x8;
typedef __attribute__((ext_vector_type(4))) short bf16x4;
typedef __attribute__((ext_vector_type(4))) float f32x4;
typedef __attribute__((ext_vector_type(4))) unsigned short u16x4;

// zero A-row page: .bss (zeroed at module load, never written)
__device__ __hip_bfloat16 g_zero[1152];

__device__ __forceinline__ short f2bf(float f) {
  union { __hip_bfloat16 b; short s; } u;
  u.b = __float2bfloat16(f);
  return u.s;
}
__device__ __forceinline__ float bf2f(unsigned short h) {
  return __uint_as_float(((unsigned)h) << 16);
}

// ---- gating: x @ gw^T (fp32) + bf16 xb + convw INTERLEAVED + FUSED top-2/softmax/importance ----
// K-chunk 64 (33.8 KB LDS, 4 blocks/CU). Per-logit FMA chain strictly k-ascending ->
// bit-identical logits. After the K-loop the block's 64x64 logits go to LDS (reusing Xs)
// and 64 threads run the SAME j-ascending top-2 scan / softmax arithmetic as the old
// topk kernel -> bit-identical routing and probs. No logits global round-trip.
__global__ __launch_bounds__(256, 4) void gating_kernel(const float* __restrict__ x,
                                                        const float* __restrict__ gw,
                                                        __hip_bfloat16* __restrict__ xb,
                                                        const float* __restrict__ ew,
                                                        __hip_bfloat16* __restrict__ wb,
                                                        int2* __restrict__ e01,
                                                        float2* __restrict__ p01,
                                                        float* __restrict__ imp_part) {
  __shared__ float Xs[64][66];
  __shared__ float Gs[64][66];
  __shared__ float v1s[64], invss[64];
  const int tid = threadIdx.x;
  const int tok0 = blockIdx.x * 64;
  const int th = tid >> 4;   // token sub-row 0..15
  const int te = tid & 15;   // expert sub-col 0..15
  float acc[4][4];
#pragma unroll
  for (int i = 0; i < 4; ++i)
#pragma unroll
    for (int j = 0; j < 4; ++j) acc[i][j] = 0.f;

  // convw: 67.1M floats / (512 blk * 256 th * 8 per step) = 64 steps; 4 per chunk
  size_t ci = ((size_t)blockIdx.x * 256 + tid) * 8;
  const size_t cstride = (size_t)512 * 256 * 8;

  for (int k0i = 0; k0i < 16; ++k0i) {
    const int k0 = k0i * 64;
#pragma unroll
    for (int r = 0; r < 4; ++r) {
      int idx = r * 256 + tid;
      int row = idx >> 4;
      int c = (idx & 15) * 4;
      float4 xv4 = *(const float4*)&x[(size_t)(tok0 + row) * HD + k0 + c];
      *(float4*)&Xs[row][c] = xv4;
      bf16x4 o;
      o[0] = f2bf(xv4.x); o[1] = f2bf(xv4.y); o[2] = f2bf(xv4.z); o[3] = f2bf(xv4.w);
      *(bf16x4*)&xb[(size_t)(tok0 + row) * HD + k0 + c] = o;
      *(float4*)&Gs[row][c] = *(const float4*)&gw[(size_t)row * HD + k0 + c];
    }
    float4 ca[2], cb[2];
#pragma unroll
    for (int q = 0; q < 2; ++q) {
      ca[q] = *(const float4*)(ew + ci + (size_t)q * cstride);
      cb[q] = *(const float4*)(ew + ci + (size_t)q * cstride + 4);
    }
    __syncthreads();
#pragma unroll 4
    for (int kk = 0; kk < 8; ++kk) {
      float4 xv[4], gv[4];
#pragma unroll
      for (int i = 0; i < 4; ++i) xv[i] = *(float4*)&Xs[th + i * 16][kk * 4];
#pragma unroll
      for (int j = 0; j < 4; ++j) gv[j] = *(float4*)&Gs[te + j * 16][kk * 4];
#pragma unroll
      for (int i = 0; i < 4; ++i)
#pragma unroll
        for (int j = 0; j < 4; ++j) {
          acc[i][j] = fmaf(xv[i].x, gv[j].x, acc[i][j]);
          acc[i][j] = fmaf(xv[i].y, gv[j].y, acc[i][j]);
          acc[i][j] = fmaf(xv[i].z, gv[j].z, acc[i][j]);
          acc[i][j] = fmaf(xv[i].w, gv[j].w, acc[i][j]);
        }
    }
#pragma unroll
    for (int q = 0; q < 2; ++q) {
      bf16x8 o;
      o[0] = f2bf(ca[q].x); o[1] = f2bf(ca[q].y); o[2] = f2bf(ca[q].z); o[3] = f2bf(ca[q].w);
      o[4] = f2bf(cb[q].x); o[5] = f2bf(cb[q].y); o[6] = f2bf(cb[q].z); o[7] = f2bf(cb[q].w);
      *(bf16x8*)(wb + ci + (size_t)q * cstride) = o;
    }
#pragma unroll
    for (int q = 0; q < 2; ++q) {
      ca[q] = *(const float4*)(ew + ci + (size_t)(q + 2) * cstride);
      cb[q] = *(const float4*)(ew + ci + (size_t)(q + 2) * cstride + 4);
    }
#pragma unroll 4
    for (int kk = 8; kk < 16; ++kk) {
      float4 xv[4], gv[4];
#pragma unroll
      for (int i = 0; i < 4; ++i) xv[i] = *(float4*)&Xs[th + i * 16][kk * 4];
#pragma unroll
      for (int j = 0; j < 4; ++j) gv[j] = *(float4*)&Gs[te + j * 16][kk * 4];
#pragma unroll
      for (int i = 0; i < 4; ++i)
#pragma unroll
        for (int j = 0; j < 4; ++j) {
          acc[i][j] = fmaf(xv[i].x, gv[j].x, acc[i][j]);
          acc[i][j] = fmaf(xv[i].y, gv[j].y, acc[i][j]);
          acc[i][j] = fmaf(xv[i].z, gv[j].z, acc[i][j]);
          acc[i][j] = fmaf(xv[i].w, gv[j].w, acc[i][j]);
        }
    }
#pragma unroll
    for (int q = 0; q < 2; ++q) {
      bf16x8 o;
      o[0] = f2bf(ca[q].x); o[1] = f2bf(ca[q].y); o[2] = f2bf(ca[q].z); o[3] = f2bf(ca[q].w);
      o[4] = f2bf(cb[q].x); o[5] = f2bf(cb[q].y); o[6] = f2bf(cb[q].z); o[7] = f2bf(cb[q].w);
      *(bf16x8*)(wb + ci + (size_t)(q + 2) * cstride) = o;
    }
    ci += (size_t)4 * cstride;
    __syncthreads();
  }

  // ---- fused top-2 + softmax + importance (logits stay in LDS) ----
  float (*Ls)[66] = Xs;  // reuse Xs storage
#pragma unroll
  for (int i = 0; i < 4; ++i)
#pragma unroll
    for (int j = 0; j < 4; ++j)
      Ls[th + i * 16][te + j * 16] = acc[i][j];
  __syncthreads();
  if (tid < 64) {
    float v1 = -1e30f; int i1 = 0;
#pragma unroll
    for (int j = 0; j < 64; ++j) { float lv = Ls[tid][j]; if (lv > v1) { v1 = lv; i1 = j; } }
    float v2 = -1e30f; int i2 = 0;
#pragma unroll
    for (int j = 0; j < 64; ++j) { float lv = Ls[tid][j]; if (j != i1 && lv > v2) { v2 = lv; i2 = j; } }
    float ex = __expf(v2 - v1);
    float inv2 = 1.f / (1.f + ex);
    e01[tok0 + tid] = make_int2(i1, i2);
    p01[tok0 + tid] = make_float2(inv2, ex * inv2);
    float s = 0.f;
#pragma unroll
    for (int j = 0; j < 64; ++j) s += __expf(Ls[tid][j] - v1);
    v1s[tid] = v1;
    invss[tid] = 1.f / s;
  }
  __syncthreads();
  if (tid < 64) {
    float imp = 0.f;
#pragma unroll
    for (int t2 = 0; t2 < 64; ++t2) imp += __expf(Ls[t2][tid] - v1s[t2]) * invss[t2];
    imp_part[(size_t)blockIdx.x * 64 + tid] = imp;
  }
}

// ------- per-tile stable rank + histogram (reads e01; rank code verified unchanged) -------
__global__ __launch_bounds__(256) void hist_rank_kernel(const int2* __restrict__ e01,
                                                        int* __restrict__ rank_buf,
                                                        int* __restrict__ hist) {
  __shared__ int wh[4][64];
  const int tid = threadIdx.x;
  const int w = tid >> 6, lane = tid & 63;
  const int t = blockIdx.x * 256 + tid;
  int2 ee = e01[t];
  const int i1 = ee.x, i2 = ee.y;
  int r0 = 0, r1 = 0, cnt = 0;
#pragma unroll
  for (int j = 0; j < 64; ++j) {
    int a = __shfl(i1, j);
    int b = __shfl(i2, j);
    int ja = (j < lane);
    r0 += ja & (a == i1);
    r0 += ja & (b == i1);
    r1 += ja & (a == i2);
    r1 += ja & (b == i2);
    cnt += (a == lane) + (b == lane);
  }
  wh[w][lane] = cnt;
  __syncthreads();
#pragma unroll
  for (int ww = 0; ww < 4; ++ww)
    if (ww < w) { r0 += wh[ww][i1]; r1 += wh[ww][i2]; }
  rank_buf[2 * t] = r0;
  rank_buf[2 * t + 1] = r1;
  if (tid < 64)
    hist[blockIdx.x * 64 + tid] = wh[0][tid] + wh[1][tid] + wh[2][tid] + wh[3][tid];
}

// ------- dispatch: per-expert exclusive scan over tiles + aux loss (folded) -------
__global__ __launch_bounds__(64) void scan_aux_kernel(const int* __restrict__ hist,
                                                      const float* __restrict__ imp_part,
                                                      int* __restrict__ tile_off,
                                                      int* __restrict__ counts,
                                                      float* __restrict__ out) {
  const int e = threadIdx.x;
  int run = 0;
  for (int t = 0; t < NTILE; ++t) {
    int h = hist[t * 64 + e];
    tile_off[t * 64 + e] = run;
    run += h;
  }
  counts[e] = run;

  float imp = 0.f;
  for (int w = 0; w < 512; ++w) imp += imp_part[(size_t)w * 64 + e];
  imp *= (1.f / (float)NTOK);
  float usage = (float)run / (float)NKF;
  float v = usage * imp;
#pragma unroll
  for (int off = 32; off; off >>= 1) v += __shfl_xor(v, off);
  if (e == 0) out[(size_t)NTOK * HD] = fminf(v * (float)NE * 0.01f, 1.0f);
}

// ------- dispatch: place -------
__global__ __launch_bounds__(256) void place_kernel(const int2* __restrict__ e01,
                                                    const int* __restrict__ rank_buf,
                                                    const int* __restrict__ tile_off,
                                                    int* __restrict__ slot_of,
                                                    int* __restrict__ slot_token) {
  const int tid = threadIdx.x;
  const int i = blockIdx.x * 256 + tid;
  int2 ee = e01[i >> 1];
  const int e = (i & 1) ? ee.y : ee.x;
  const int pos = tile_off[(i >> 9) * 64 + e] + rank_buf[i];
  const int slot = (pos < CAP) ? (e * CAP + pos) : -1;
  slot_of[i] = slot;
  if (slot >= 0) slot_token[slot] = i;
}

// -------- grouped expert GEMM: 256x256, BK=64, 8-wave, fused A-gather, 3-buf B ring --------
#define ASYNC16(g, l) __builtin_amdgcn_global_load_lds( \
    (const __attribute__((address_space(1))) void*)(g), \
    (__attribute__((address_space(3))) void*)(l), 16, 0, 0)

#define STAGE_A(buf, ks, kcol) do {                                             \
    const int _d = ((buf) * 16384 + (ks) * 8192 + wuni) * 2;                    \
    ASYNC16(arow0 + (kcol) + (ks) * 32 + sw8, (char*)lds + _d);                 \
    ASYNC16(arow1 + (kcol) + (ks) * 32 + sw8, (char*)lds + _d + 8192);          \
  } while (0)

#define STAGE_B3(buf3, ks, kcol) do {                                           \
    const __hip_bfloat16* _g = B + (size_t)srow * HD + (kcol) + (ks) * 32 + sw8; \
    const int _d = (32768 + (buf3) * 16384 + (ks) * 8192 + wuni) * 2;           \
    ASYNC16(_g, (char*)lds + _d);                                               \
    ASYNC16(_g + (size_t)128 * HD, (char*)lds + _d + 8192);                     \
  } while (0)

#define LDA(dst, buf, ks, mi) \
  dst = *(const bf16x8*)(lds + (buf) * 16384 + (ks) * 8192 + (wm * 128 + (mi) * 16 + fr) * 32 + rsw)
#define LDB3(dst, buf3, ks, ni) \
  dst = *(const bf16x8*)(lds + 32768 + (buf3) * 16384 + (ks) * 8192 + (wn * 64 + (ni) * 16 + fr) * 32 + rsw)

#define MFMA_HALF(h)                                                            \
  _Pragma("unroll")                                                             \
  for (int mm = 0; mm < 4; ++mm)                                                \
    _Pragma("unroll")                                                           \
    for (int nn = 0; nn < 4; ++nn)                                              \
      acc[(h) * 4 + mm][nn] =                                                   \
          __builtin_amdgcn_mfma_f32_16x16x32_bf16(av[mm], bv[nn], acc[(h) * 4 + mm][nn], 0, 0, 0)

#define BARX() do { asm volatile("" ::: "memory"); __builtin_amdgcn_s_barrier(); asm volatile("" ::: "memory"); } while (0)
#define VMC(n) asm volatile("s_waitcnt vmcnt(" #n ")" ::: "memory")

__global__ __launch_bounds__(512, 2) void moe_gemm_kernel(const __hip_bfloat16* __restrict__ xb,
                                                          const int* __restrict__ slot_token,
                                                          const __hip_bfloat16* __restrict__ Wb,
                                                          const int* __restrict__ counts,
                                                          __hip_bfloat16* __restrict__ Eo) {
  __shared__ __hip_bfloat16 lds[81920];  // 160 KB exactly

  const int bid = blockIdx.x;
  const int swz = (bid & 7) * 160 + (bid >> 3);
  const int e = swz / 20;
  const int t20 = swz - e * 20;
  const int tm = t20 >> 2, tn = t20 & 3;

  const int cnt = counts[e];
  if (tm * 256 >= cnt) return;  // capacity-tile skip

  const int tid = threadIdx.x;
  const int lane = tid & 63;
  const int w = tid >> 6;
  const int wm = w >> 2, wn = w & 3;

  const __hip_bfloat16* B = Wb + (size_t)e * HD * HD + (size_t)(tn * 256) * HD;

  const int srow = tid >> 2;
  const int sw8 = ((tid & 3) ^ ((tid >> 3) & 3)) * 8;
  const int wuni = w * 512;

  const int slotbase = e * CAP + tm * 256;
  const int r0row = tm * 256 + srow;
  const int i0 = slot_token[slotbase + srow];
  const int i1 = slot_token[slotbase + 128 + srow];
  const __hip_bfloat16* arow0 = (r0row < cnt) ? xb + (size_t)(i0 >> 1) * HD : g_zero;
  const __hip_bfloat16* arow1 = (r0row + 128 < cnt) ? xb + (size_t)(i1 >> 1) * HD : g_zero;

  const int fr = lane & 15;
  const int fq = lane >> 4;
  const int rsw = (fq ^ ((fr >> 1) & 3)) * 8;

  f32x4 acc[8][4] = {};

  STAGE_A(0, 0, 0);
  STAGE_A(0, 1, 0);
  STAGE_B3(0, 0, 0);
  STAGE_B3(0, 1, 0);
  STAGE_B3(1, 0, 64);
  STAGE_B3(1, 1, 64);
  VMC(4);
  BARX();

#pragma unroll 2
  for (int t = 0; t < 16; ++t) {
    const int ard = t & 1, ast = ard ^ 1;
    const int b_rd = t % 3;
    int b_st = b_rd + 2; if (b_st >= 3) b_st -= 3;
    const int kcA = (t + 1) * 64;
    const int kcB = (t + 2) * 64;
    const bool hA = (t < 15);
    const bool hB = (t < 14);
    bf16x8 av[4], bv[4];

    LDB3(bv[0], b_rd, 0, 0); LDB3(bv[1], b_rd, 0, 1); LDB3(bv[2], b_rd, 0, 2); LDB3(bv[3], b_rd, 0, 3);
    LDA(av[0], ard, 0, 0); LDA(av[1], ard, 0, 1); LDA(av[2], ard, 0, 2); LDA(av[3], ard, 0, 3);
    if (hA) STAGE_A(ast, 0, kcA);
    BARX();
    __builtin_amdgcn_s_setprio(1);
    MFMA_HALF(0);
    __builtin_amdgcn_s_setprio(0);
    BARX();

    LDA(av[0], ard, 0, 4); LDA(av[1], ard, 0, 5); LDA(av[2], ard, 0, 6); LDA(av[3], ard, 0, 7);
    if (hB) {
      STAGE_B3(b_st, 0, kcB);
      VMC(6);
    } else if (t == 14) {
      VMC(4);
    } else {
      VMC(0);
    }
    BARX();
    __builtin_amdgcn_s_setprio(1);
    MFMA_HALF(1);
    __builtin_amdgcn_s_setprio(0);
    BARX();

    LDB3(bv[0], b_rd, 1, 0); LDB3(bv[1], b_rd, 1, 1); LDB3(bv[2], b_rd, 1, 2); LDB3(bv[3], b_rd, 1, 3);
    LDA(av[0], ard, 1, 0); LDA(av[1], ard, 1, 1); LDA(av[2], ard, 1, 2); LDA(av[3], ard, 1, 3);
    if (hA) STAGE_A(ast, 1, kcA);
    BARX();
    __builtin_amdgcn_s_setprio(1);
    MFMA_HALF(0);
    __builtin_amdgcn_s_setprio(0);
    BARX();

    LDA(av[0], ard, 1, 4); LDA(av[1], ard, 1, 5); LDA(av[2], ard, 1, 6); LDA(av[3], ard, 1, 7);
    if (hB) {
      STAGE_B3(b_st, 1, kcB);
      VMC(6);
    } else if (t == 14) {
      VMC(2);
    }
    BARX();
    __builtin_amdgcn_s_setprio(1);
    MFMA_HALF(1);
    __builtin_amdgcn_s_setprio(0);
    BARX();
  }

  __hip_bfloat16* C = Eo + (size_t)e * CAP * HD +
                      (size_t)(tm * 256 + wm * 128) * HD + tn * 256 + wn * 64;
#pragma unroll
  for (int m = 0; m < 8; ++m)
#pragma unroll
    for (int n = 0; n < 4; ++n)
#pragma unroll
      for (int r = 0; r < 4; ++r)
        C[(size_t)(m * 16 + fq * 4 + r) * HD + n * 16 + fr] = __float2bfloat16(acc[m][n][r]);
}

// ---------------- combine ----------------
__global__ __launch_bounds__(256) void combine_kernel(const __hip_bfloat16* __restrict__ eo,
                                                      const int* __restrict__ slot_of,
                                                      const float2* __restrict__ p01,
                                                      float* __restrict__ out) {
  const int t = blockIdx.x;
  const int tid = threadIdx.x;
  const float2 p = p01[t];
  const int s0 = slot_of[2 * t], s1 = slot_of[2 * t + 1];
  float a0 = 0.f, a1 = 0.f, a2 = 0.f, a3 = 0.f;
  if (s0 >= 0) {
    u16x4 v = *(const u16x4*)((const unsigned short*)eo + (size_t)s0 * HD + tid * 4);
    a0 += p.x * bf2f(v[0]); a1 += p.x * bf2f(v[1]);
    a2 += p.x * bf2f(v[2]); a3 += p.x * bf2f(v[3]);
  }
  if (s1 >= 0) {
    u16x4 v = *(const u16x4*)((const unsigned short*)eo + (size_t)s1 * HD + tid * 4);
    a0 += p.y * bf2f(v[0]); a1 += p.y * bf2f(v[1]);
    a2 += p.y * bf2f(v[2]); a3 += p.y * bf2f(v[3]);
  }
  float4 res = make_float4(a0, a1, a2, a3);
  *(float4*)(out + (size_t)t * HD + tid * 4) = res;
}

extern "C" void kernel_launch(void* const* d_in, const int* in_sizes, int n_in,
                              void* d_out, int out_size, void* d_ws, size_t ws_size,
                              hipStream_t stream) {
  const float* x = (const float*)d_in[0];
  const float* gw = (const float*)d_in[1];
  const float* ew = (const float*)d_in[2];
  float* out = (float*)d_out;

  char* p = (char*)d_ws;
  int2* e01 = (int2*)p;                 p += (size_t)NTOK * 8;
  float2* p01 = (float2*)p;             p += (size_t)NTOK * 8;
  int* slot_of = (int*)p;               p += (size_t)NKF * 4;
  int* slot_token = (int*)p;            p += (size_t)NSLOT * 4;
  int* counts = (int*)p;                p += 256;
  float* imp_part = (float*)p;          p += (size_t)512 * 64 * 4;
  int* rank_buf = (int*)p;              p += (size_t)NKF * 4;
  int* hist = (int*)p;                  p += (size_t)NTILE * 64 * 4;
  int* tile_off = (int*)p;              p += (size_t)NTILE * 64 * 4;
  __hip_bfloat16* xb = (__hip_bfloat16*)p; p += (size_t)NTOK * HD * 2;
  __hip_bfloat16* Wb = (__hip_bfloat16*)p;  p += (size_t)NE * HD * HD * 2;
  __hip_bfloat16* Eo = (__hip_bfloat16*)p;  p += (size_t)NSLOT * HD * 2;

  gating_kernel<<<NTOK / 64, 256, 0, stream>>>(x, gw, xb, ew, Wb, e01, p01, imp_part);
  hist_rank_kernel<<<NTOK / 256, 256, 0, stream>>>(e01, rank_buf, hist);
  scan_aux_kernel<<<1, 64, 0, stream>>>(hist, imp_part, tile_off, counts, out);
  place_kernel<<<NKF / 256, 256, 0, stream>>>(e01, rank_buf, tile_off, slot_of, slot_token);
  moe_gemm_kernel<<<dim3(1280), 512, 0, stream>>>(xb, slot_token, Wb, counts, Eo);
  combine_kernel<<<NTOK, 256, 0, stream>>>(Eo, slot_of, p01, out);
}